// Round 1
// baseline (108.409 us; speedup 1.0000x reference)
//
#include <hip/hip_runtime.h>

#define FDIM 1024
#define CDIM 64

// order-preserving float <-> uint encoding (monotonic under unsigned compare)
__device__ __forceinline__ unsigned encf(float x) {
    unsigned b = __float_as_uint(x);
    return (b & 0x80000000u) ? ~b : (b | 0x80000000u);
}
__device__ __forceinline__ float decf(unsigned k) {
    unsigned b = (k & 0x80000000u) ? (k ^ 0x80000000u) : ~k;
    return __uint_as_float(b);
}

// Tiny precompute: seg[f] = argmax_c mask[f, c] (mask rows are one-hot).
// Also zeroes the scalar output (harness poisons d_out once, never re-poisons).
__global__ void seg_kernel(const float* __restrict__ mask, int* __restrict__ seg,
                           float* __restrict__ out) {
    if (blockIdx.x == 0 && threadIdx.x == 0) out[0] = 0.f;
    int f = blockIdx.x * blockDim.x + threadIdx.x;
    if (f < FDIM) {
        const float* r = mask + (size_t)f * CDIM;
        int s = 0;
        #pragma unroll 8
        for (int c = 0; c < CDIM; ++c)
            if (r[c] > 0.5f) s = c;
        seg[f] = s;
    }
}

__global__ __launch_bounds__(256) void mix_main(
    const float* __restrict__ logits, const int* __restrict__ labels,
    const int* __restrict__ seg, float* __restrict__ out,
    int rows, int rowsPerWave)
{
    __shared__ unsigned gmaxBuf[4][CDIM];      // one 64-slot segment-max array per wave
    const int lane  = threadIdx.x & 63;
    const int wslot = threadIdx.x >> 6;
    unsigned* gm = gmaxBuf[wslot];
    const int wid = blockIdx.x * (blockDim.x >> 6) + wslot;

    // seg ids for this lane's 16 fine indices: f = (k*64+lane)*4 + e  (row-invariant)
    int segs[16];
    #pragma unroll
    for (int k = 0; k < 4; ++k) {
        int4 sv = reinterpret_cast<const int4*>(seg)[k * 64 + lane];
        segs[k * 4 + 0] = sv.x; segs[k * 4 + 1] = sv.y;
        segs[k * 4 + 2] = sv.z; segs[k * 4 + 3] = sv.w;
    }

    float acc = 0.f;
    const int rowStart = wid * rowsPerWave;

    for (int r = 0; r < rowsPerWave; ++r) {
        const int row = rowStart + r;
        if (row >= rows) break;

        // coalesced: 4 x float4 per lane = the whole 4 KB row per wave
        const float4* rp = reinterpret_cast<const float4*>(logits + (size_t)row * FDIM);
        float xv[16];
        #pragma unroll
        for (int k = 0; k < 4; ++k) {
            float4 v = rp[k * 64 + lane];
            xv[k * 4 + 0] = v.x; xv[k * 4 + 1] = v.y;
            xv[k * 4 + 2] = v.z; xv[k * 4 + 3] = v.w;
        }

        // segment max over groups via LDS uint atomics (lane c owns slot c)
        gm[lane] = 0u;                          // enc(-inf) lower bound
        asm volatile("s_waitcnt lgkmcnt(0)" ::: "memory");
        #pragma unroll
        for (int e = 0; e < 16; ++e)
            atomicMax(&gm[segs[e]], encf(xv[e]));
        asm volatile("s_waitcnt lgkmcnt(0)" ::: "memory");

        float gmc = decf(gm[lane]);             // coarse_max[lane] (every group non-empty)
        float m = gmc;                          // global max = max over groups
        #pragma unroll
        for (int off = 32; off; off >>= 1) m = fmaxf(m, __shfl_xor(m, off));

        const int lab = labels[row];

        float zp = 0.f, sp = 0.f;
        #pragma unroll
        for (int e = 0; e < 16; ++e) {
            float ev = __expf(xv[e] - m);
            zp += ev;
            sp += (segs[e] == lab) ? ev : 0.f;
        }
        float zc = __expf(gmc - m);

        #pragma unroll
        for (int off = 32; off; off >>= 1) {
            zp += __shfl_xor(zp, off);          // Z
            sp += __shfl_xor(sp, off);          // S_label
            zc += __shfl_xor(zc, off);          // sum_c exp(gmax_c - m)
        }
        float cml = __shfl(gmc, lab);           // coarse_max[label]

        // ce = m + log(Zc) - cm[lab];  nll = log(Z) - log(S_lab)
        acc += (m + __logf(zc) - cml) + (__logf(zp) - __logf(sp));
    }

    if (lane == 0) atomicAdd(out, acc * (0.5f / (float)rows));
}

extern "C" void kernel_launch(void* const* d_in, const int* in_sizes, int n_in,
                              void* d_out, int out_size, void* d_ws, size_t ws_size,
                              hipStream_t stream) {
    const float* logits = (const float*)d_in[0];
    const int*   labels = (const int*)d_in[1];
    const float* mask   = (const float*)d_in[2];
    float* out = (float*)d_out;
    int*   seg = (int*)d_ws;                    // 1024 ints = 4 KB scratch

    const int rows = in_sizes[1];               // B*S

    seg_kernel<<<4, 256, 0, stream>>>(mask, seg, out);

    const int blocks = 1024;                    // 4 waves/block -> 4096 waves
    const int wavesTotal = blocks * 4;
    const int rowsPerWave = (rows + wavesTotal - 1) / wavesTotal;   // 16
    mix_main<<<blocks, 256, 0, stream>>>(logits, labels, seg, out, rows, rowsPerWave);
}